// Round 11
// baseline (200.985 us; speedup 1.0000x reference)
//
#include <hip/hip_runtime.h>

typedef unsigned short u16;
typedef __bf16 bf16x8 __attribute__((ext_vector_type(8)));
typedef float f32x4 __attribute__((ext_vector_type(4)));

#define D_MODEL 768
#define NH 12
#define SEQ 2048
#define BB 4
// 1/sqrt(64) * log2(e): softmax runs in exp2 domain (folded into W_Q, b_Q)
#define QSCALE 0.18033688011112042f
#define FIXM 8.0f  // fixed softmax max (exp2 domain); scores ~N(0,0.44)

__device__ __forceinline__ u16 f2b(float f) {
  __bf16 h = (__bf16)f;
  return __builtin_bit_cast(u16, h);
}

__device__ __forceinline__ void gload16(const void* g, void* l) {
  __builtin_amdgcn_global_load_lds((__attribute__((address_space(1))) void*)g,
                                   (__attribute__((address_space(3))) void*)l, 16, 0, 0);
}

__device__ __forceinline__ f32x4 mm16(bf16x8 a, bf16x8 b, f32x4 c) {
  return __builtin_amdgcn_mfma_f32_16x16x32_bf16(a, b, c, 0, 0, 0);
}

// ---------------- prep: cast x, pack weights, pack biases ----------------
__global__ void prep_kernel(const float* __restrict__ x, const float* __restrict__ wq,
                            const float* __restrict__ wk, const float* __restrict__ wv,
                            const float* __restrict__ wo, const float* __restrict__ bq,
                            const float* __restrict__ bk, const float* __restrict__ bv,
                            u16* __restrict__ xb, u16* __restrict__ wt,
                            u16* __restrict__ wot, float* __restrict__ qkvb) {
  const int bid = blockIdx.x;
  if (bid < 6144) {
    int i = (bid * 256 + threadIdx.x) * 4;
    float4 v = *(const float4*)&x[i];
    ushort4 o;
    o.x = f2b(v.x); o.y = f2b(v.y); o.z = f2b(v.z); o.w = f2b(v.w);
    *(ushort4*)&xb[i] = o;
  } else {
    int i = (bid - 6144) * 256 + threadIdx.x;
    {
      int cp = i / 768, d = i % 768;
      int proj = cp / 768, c = cp % 768, h = c / 64, e = c % 64;
      const float* W = (proj == 0) ? wq : ((proj == 1) ? wk : wv);
      float v = W[(size_t)h * 49152 + d * 64 + e];
      if (proj == 0) v *= QSCALE;
      wt[i] = f2b(v);
    }
    if (i < 768 * 768) {
      int rp = i / 768, d = i % 768;
      wot[i] = f2b(wo[(size_t)d * 768 + rp]);  // wot[d'][c]: rp=row d', d=col c
    }
    if (i < 2304) {
      int proj = i / 768, c = i % 768;
      float v = (proj == 0) ? bq[c] * QSCALE : ((proj == 1) ? bk[c] : bv[c]);
      qkvb[i] = v;
    }
  }
}

// ---------------- fused QKV GEMM — 4-buffer, 3-deep prefetch, 1 barrier/step ----
// C[c' 2304][token 8192] = wt * xb^T. 128x128 tile, 4 waves, BK=32.
// Per step: vmcnt(8/4/0) -> s_barrier -> stage tile kt+3 -> ds_read+MFMA.
// Loads get ~3 steps of slack (covers HBM-miss latency from L2 write-pollution).
__global__ __launch_bounds__(256) void gemm_qkv_kernel(
    const u16* __restrict__ A, const u16* __restrict__ Bt,
    const float* __restrict__ qkvb, u16* __restrict__ qw, u16* __restrict__ kw,
    u16* __restrict__ vw) {
  __shared__ u16 lds[32768];  // 64KB: A bufs 0-3 at [b*4096], B at [16384+b*4096]
  const int tid = threadIdx.x;
  const int w = tid >> 6, lane = tid & 63;
  const int lg = lane >> 4, cl = lane & 15;
  // XCD-chunked swizzle: 1152 blocks, 144/XCD; bm fast (wt panel L2-resident)
  const int L = blockIdx.x;
  const int v = (L & 7) * 144 + (L >> 3);
  const int bm = v % 18, bn = v / 18;
  const int wr = w >> 1, wc = w & 1;
  const int NK = D_MODEL / 32;  // 24

  f32x4 vzero = {0.f, 0.f, 0.f, 0.f};
  f32x4 acc[4][4];
#pragma unroll
  for (int mi = 0; mi < 4; mi++)
#pragma unroll
    for (int ni = 0; ni < 4; ni++) acc[mi][ni] = vzero;

  const u16* aB = A + (size_t)bm * 128 * D_MODEL;
  const u16* bB = Bt + (size_t)bn * 128 * D_MODEL;

  auto stage = [&](int buf, int kt) {
    const int kof = kt * 32 + w * 8;
    gload16(aB + (size_t)(lane)*D_MODEL + kof, &lds[buf * 4096 + (w * 128 + 0) * 8]);
    gload16(aB + (size_t)(64 + lane) * D_MODEL + kof,
            &lds[buf * 4096 + (w * 128 + 64) * 8]);
    gload16(bB + (size_t)(lane)*D_MODEL + kof,
            &lds[16384 + buf * 4096 + (w * 128 + 0) * 8]);
    gload16(bB + (size_t)(64 + lane) * D_MODEL + kof,
            &lds[16384 + buf * 4096 + (w * 128 + 64) * 8]);
  };

  stage(0, 0);
  stage(1, 1);
  stage(2, 2);
  for (int kt = 0; kt < NK; ++kt) {
    const int cur = kt & 3;
    const int rem = NK - 1 - kt;  // tiles prefetched beyond kt
    if (rem >= 2) asm volatile("s_waitcnt vmcnt(8)" ::: "memory");
    else if (rem == 1) asm volatile("s_waitcnt vmcnt(4)" ::: "memory");
    else asm volatile("s_waitcnt vmcnt(0)" ::: "memory");
    __builtin_amdgcn_s_barrier();  // every wave's tile-kt loads landed; prev reads done
    __builtin_amdgcn_sched_barrier(0);
    if (kt + 3 < NK) stage((kt + 3) & 3, kt + 3);  // targets buf (kt-1)&3: free

    bf16x8 af[4], bf4[4];
#pragma unroll
    for (int mi = 0; mi < 4; mi++)
      af[mi] = *(const bf16x8*)&lds[cur * 4096 + (lg * 128 + wr * 64 + mi * 16 + cl) * 8];
#pragma unroll
    for (int ni = 0; ni < 4; ni++)
      bf4[ni] = *(const bf16x8*)&lds[16384 + cur * 4096 +
                                     (lg * 128 + wc * 64 + ni * 16 + cl) * 8];
    __builtin_amdgcn_s_setprio(1);
#pragma unroll
    for (int mi = 0; mi < 4; mi++)
#pragma unroll
      for (int ni = 0; ni < 4; ni++)
        acc[mi][ni] = mm16(af[mi], bf4[ni], acc[mi][ni]);
    __builtin_amdgcn_s_setprio(0);
  }

  __syncthreads();  // staging LDS now reusable as epilogue scratch
  u16* lw = &lds[w * 4096];  // 8KB per-wave scratch
  const int cm = bm * 128 + wr * 64;  // c' base: exactly one (proj, head)
  const int cn = bn * 128 + wc * 64;  // token base: within one batch b
  const int proj = cm / 768;
  const int h = (cm % 768) >> 6;
  const int b = cn >> 11, s_base = cn & 2047;
  const int rlo = lane >> 3, q8 = lane & 7;

  float bz[4][4];
#pragma unroll
  for (int mi = 0; mi < 4; mi++) {
    float4 b4 = *(const float4*)&qkvb[cm + mi * 16 + lg * 4];
    bz[mi][0] = b4.x; bz[mi][1] = b4.y; bz[mi][2] = b4.z; bz[mi][3] = b4.w;
  }

  if (proj < 2) {
    // LDS [s_local][e x 128B]; acc row = e, col = s -> pack 4 e's per write
#pragma unroll
    for (int mi = 0; mi < 4; mi++) {
      const int e0 = mi * 16 + lg * 4;
#pragma unroll
      for (int ni = 0; ni < 4; ni++) {
        const int s_l = ni * 16 + cl;
        ushort4 pk;
        pk.x = f2b(acc[mi][ni][0] + bz[mi][0]);
        pk.y = f2b(acc[mi][ni][1] + bz[mi][1]);
        pk.z = f2b(acc[mi][ni][2] + bz[mi][2]);
        pk.w = f2b(acc[mi][ni][3] + bz[mi][3]);
        *(ushort4*)&lw[(s_l * 128 + ((e0 * 2) ^ ((s_l & 7) << 4))) >> 1] = pk;
      }
    }
    u16* dst = ((proj == 0) ? qw : kw) + (((size_t)(b * NH + h) * SEQ + s_base) << 6);
#pragma unroll
    for (int it = 0; it < 8; it++) {
      const int row = it * 8 + rlo;
      *(bf16x8*)&dst[row * 64 + q8 * 8] =
          *(const bf16x8*)&lw[(row * 128 + ((q8 * 16) ^ ((row & 7) << 4))) >> 1];
    }
  } else {
    // V: LDS [e][s x 128B]; coalesced b128 readout along s
#pragma unroll
    for (int mi = 0; mi < 4; mi++)
#pragma unroll
      for (int ni = 0; ni < 4; ni++) {
        const int s_l = ni * 16 + cl;
#pragma unroll
        for (int r = 0; r < 4; r++) {
          const int e_l = mi * 16 + lg * 4 + r;
          lw[(e_l * 128 + ((s_l * 2) ^ ((e_l & 7) << 4))) >> 1] =
              f2b(acc[mi][ni][r] + bz[mi][r]);
        }
      }
    u16* dst = vw + (((size_t)(b * NH + h)) << 17) + s_base;
#pragma unroll
    for (int it = 0; it < 8; it++) {
      const int row = it * 8 + rlo;  // e
      *(bf16x8*)&dst[((size_t)row << 11) + q8 * 8] =
          *(const bf16x8*)&lw[(row * 128 + ((q8 * 16) ^ ((row & 7) << 4))) >> 1];
    }
  }
}

// ---------------- out-proj GEMM — same 4-buffer 3-deep structure ----------------
__global__ __launch_bounds__(256) void gemm_out_kernel(
    const u16* __restrict__ A, const u16* __restrict__ Bt,
    const float* __restrict__ bias0, float* __restrict__ outf) {
  __shared__ u16 lds[32768];
  const int tid = threadIdx.x;
  const int w = tid >> 6, lane = tid & 63;
  const int lg = lane >> 4, cl = lane & 15;
  const int L = blockIdx.x;
  const int v = (L & 7) * 48 + (L >> 3);
  const int bn = v % 6, bm = v / 6;
  const int wr = w >> 1, wc = w & 1;
  const int NK = D_MODEL / 32;

  f32x4 vzero = {0.f, 0.f, 0.f, 0.f};
  f32x4 acc[4][4];
#pragma unroll
  for (int mi = 0; mi < 4; mi++)
#pragma unroll
    for (int ni = 0; ni < 4; ni++) acc[mi][ni] = vzero;

  const u16* aB = A + (size_t)bm * 128 * D_MODEL;
  const u16* bB = Bt + (size_t)bn * 128 * D_MODEL;

  auto stage = [&](int buf, int kt) {
    const int kof = kt * 32 + w * 8;
    gload16(aB + (size_t)(lane)*D_MODEL + kof, &lds[buf * 4096 + (w * 128 + 0) * 8]);
    gload16(aB + (size_t)(64 + lane) * D_MODEL + kof,
            &lds[buf * 4096 + (w * 128 + 64) * 8]);
    gload16(bB + (size_t)(lane)*D_MODEL + kof,
            &lds[16384 + buf * 4096 + (w * 128 + 0) * 8]);
    gload16(bB + (size_t)(64 + lane) * D_MODEL + kof,
            &lds[16384 + buf * 4096 + (w * 128 + 64) * 8]);
  };

  stage(0, 0);
  stage(1, 1);
  stage(2, 2);
  for (int kt = 0; kt < NK; ++kt) {
    const int cur = kt & 3;
    const int rem = NK - 1 - kt;
    if (rem >= 2) asm volatile("s_waitcnt vmcnt(8)" ::: "memory");
    else if (rem == 1) asm volatile("s_waitcnt vmcnt(4)" ::: "memory");
    else asm volatile("s_waitcnt vmcnt(0)" ::: "memory");
    __builtin_amdgcn_s_barrier();
    __builtin_amdgcn_sched_barrier(0);
    if (kt + 3 < NK) stage((kt + 3) & 3, kt + 3);

    bf16x8 af[4], bf4[4];
#pragma unroll
    for (int mi = 0; mi < 4; mi++)
      af[mi] = *(const bf16x8*)&lds[cur * 4096 + (lg * 128 + wr * 64 + mi * 16 + cl) * 8];
#pragma unroll
    for (int ni = 0; ni < 4; ni++)
      bf4[ni] = *(const bf16x8*)&lds[16384 + cur * 4096 +
                                     (lg * 128 + wc * 64 + ni * 16 + cl) * 8];
    __builtin_amdgcn_s_setprio(1);
#pragma unroll
    for (int mi = 0; mi < 4; mi++)
#pragma unroll
      for (int ni = 0; ni < 4; ni++)
        acc[mi][ni] = mm16(af[mi], bf4[ni], acc[mi][ni]);
    __builtin_amdgcn_s_setprio(0);
  }

  __syncthreads();
  u16* lw = &lds[w * 4096];
  float* lwf = (float*)lw;
  const int m_base = bm * 128 + wr * 64;
  const int n0 = bn * 128 + wc * 64;
  const int rlo = lane >> 3, q8 = lane & 7;
#pragma unroll
  for (int hh = 0; hh < 2; hh++) {
#pragma unroll
    for (int nn = 0; nn < 2; nn++) {
      const int ni = hh * 2 + nn;
      const float bz = bias0[n0 + ni * 16 + cl];
      const int col = nn * 16 + cl;
#pragma unroll
      for (int mi = 0; mi < 4; mi++)
#pragma unroll
        for (int r = 0; r < 4; r++) {
          const int row = mi * 16 + lg * 4 + r;
          lwf[(row * 128 + ((col * 4) ^ ((row & 7) << 4))) >> 2] = acc[mi][ni][r] + bz;
        }
    }
#pragma unroll
    for (int it = 0; it < 8; it++) {
      const int row = it * 8 + rlo;
      const int byt = row * 128 + ((q8 * 16) ^ ((row & 7) << 4));
      *(float4*)&outf[(size_t)(m_base + row) * D_MODEL + n0 + hh * 32 + q8 * 4] =
          *(const float4*)((const char*)lwf + byt);
    }
  }
}

// ---------------- flash attention — 3-buffer, 2-deep prefetch, 1 barrier/tile ----
__global__ __launch_bounds__(256) void attn_kernel(
    const u16* __restrict__ q_ws, const u16* __restrict__ k_ws,
    const u16* __restrict__ vT_ws, u16* __restrict__ z_ws) {
  __shared__ u16 lk[3][4096];  // [buf][e-chunk][k-row][8 e]
  __shared__ u16 lv[3][4096];  // [buf][kk-chunk][e-row][8 kk]
  __shared__ u16 lp[4096];     // per-wave P [16 q][64 kk] bf16, XOR-swizzled
  const int tid = threadIdx.x, w = tid >> 6, lane = tid & 63;
  const int lg = lane >> 4, cl = lane & 15, c7 = cl & 7;
  const int L = blockIdx.x;
  const int vv = (L & 7) * 96 + (L >> 3);
  const int pair = vv & 15, bh = vv >> 4;
  const u16* qp = q_ws + (size_t)bh * SEQ * 64;
  const u16* kp = k_ws + (size_t)bh * SEQ * 64;
  const u16* vp = vT_ws + (size_t)bh * 64 * SEQ;
  const int b = bh / NH, h = bh % NH;

  for (int sel = 0; sel < 2; ++sel) {
    const int qt = (sel == 0) ? pair : 31 - pair;
    const int q0 = qt * 64;
    const int qabs = q0 + w * 16 + cl;  // this lane's q-row

    bf16x8 qf[2];
#pragma unroll
    for (int ks = 0; ks < 2; ks++)
      qf[ks] = *(const bf16x8*)&qp[(size_t)(q0 + w * 16 + cl) * 64 + ks * 32 + lg * 8];

    f32x4 vzero = {0.f, 0.f, 0.f, 0.f};
    f32x4 accO[4];
#pragma unroll
    for (int nb = 0; nb < 4; nb++) accO[nb] = vzero;
    float lrun = 0.f;

    auto stage = [&](int buf, int kt) {
      const int kn = kt * 64;
#pragma unroll
      for (int c2 = 0; c2 < 2; c2++) {
        const int ch = w + c2 * 4;
        gload16(kp + (size_t)(kn + lane) * 64 + ch * 8, &lk[buf][ch * 64 * 8]);
        gload16(vp + (size_t)lane * SEQ + kn + ch * 8, &lv[buf][ch * 64 * 8]);
      }
    };

    stage(0, 0);
    if (qt >= 1) stage(1, 1);
    int bcur = 0, bnxt = 2;
    for (int kt = 0; kt <= qt; ++kt) {
      const int k0 = kt * 64;
      if (kt < qt) asm volatile("s_waitcnt vmcnt(4)" ::: "memory");
      else asm volatile("s_waitcnt vmcnt(0)" ::: "memory");
      __builtin_amdgcn_s_barrier();  // tile kt landed for all waves; buf bnxt free
      __builtin_amdgcn_sched_barrier(0);
      if (kt + 2 <= qt) stage(bnxt, kt + 2);

      // S^T = K * Q^T: D row = kk (cb*16+lg*4+r), col = q (cl)
      f32x4 sa[4];
#pragma unroll
      for (int cb = 0; cb < 4; cb++) sa[cb] = vzero;
      __builtin_amdgcn_s_setprio(1);
#pragma unroll
      for (int ks = 0; ks < 2; ks++) {
#pragma unroll
        for (int cb = 0; cb < 4; cb++) {
          bf16x8 kf = *(const bf16x8*)&lk[bcur][((ks * 4 + lg) * 64 + cb * 16 + cl) * 8];
          sa[cb] = mm16(kf, qf[ks], sa[cb]);
        }
      }
      __builtin_amdgcn_s_setprio(0);
      if (kt == qt) {  // diagonal tile: causal mask (kk > q)
#pragma unroll
        for (int cb = 0; cb < 4; cb++)
#pragma unroll
          for (int r = 0; r < 4; r++)
            if (k0 + cb * 16 + lg * 4 + r > qabs) sa[cb][r] = -1e30f;
      }

      // fixed-max softmax: p = exp2(s - FIXM)
      float ps = 0.f;
#pragma unroll
      for (int cb = 0; cb < 4; cb++) {
        float p0 = __builtin_amdgcn_exp2f(sa[cb][0] - FIXM);
        float p1 = __builtin_amdgcn_exp2f(sa[cb][1] - FIXM);
        float p2 = __builtin_amdgcn_exp2f(sa[cb][2] - FIXM);
        float p3 = __builtin_amdgcn_exp2f(sa[cb][3] - FIXM);
        ps += (p0 + p1) + (p2 + p3);
        ushort4 pk;
        pk.x = f2b(p0); pk.y = f2b(p1); pk.z = f2b(p2); pk.w = f2b(p3);
        *(ushort4*)&lp[w * 1024 + (cl * 128 + ((cb * 32 + lg * 8) ^ (c7 << 4))) / 2] = pk;
      }
      ps += __shfl_xor(ps, 16);
      ps += __shfl_xor(ps, 32);
      lrun += ps;

      // PV: A = P (row q=cl), B = V^T
      __builtin_amdgcn_s_setprio(1);
#pragma unroll
      for (int ks = 0; ks < 2; ks++) {
        bf16x8 pf = *(const bf16x8*)&lp[w * 1024 +
                                        (cl * 128 + ((ks * 64 + lg * 16) ^ (c7 << 4))) / 2];
#pragma unroll
        for (int nb = 0; nb < 4; nb++) {
          bf16x8 vf = *(const bf16x8*)&lv[bcur][((ks * 4 + lg) * 64 + nb * 16 + cl) * 8];
          accO[nb] = mm16(pf, vf, accO[nb]);
        }
      }
      __builtin_amdgcn_s_setprio(0);

      bcur = (bcur == 2) ? 0 : bcur + 1;
      bnxt = (bnxt == 2) ? 0 : bnxt + 1;
    }

    float inv[4];
#pragma unroll
    for (int r = 0; r < 4; r++) inv[r] = 1.f / __shfl(lrun, lg * 4 + r);
#pragma unroll
    for (int nb = 0; nb < 4; nb++)
#pragma unroll
      for (int r = 0; r < 4; r++) {
        const int qrow = q0 + w * 16 + lg * 4 + r;
        z_ws[((size_t)b * SEQ + qrow) * D_MODEL + h * 64 + nb * 16 + cl] =
            f2b(accO[nb][r] * inv[r]);
      }
    // ensure this sel's prefetches are drained before reusing buffers
    asm volatile("s_waitcnt vmcnt(0)" ::: "memory");
    __builtin_amdgcn_s_barrier();
  }
}

// ---------------- launch ----------------
extern "C" void kernel_launch(void* const* d_in, const int* in_sizes, int n_in,
                              void* d_out, int out_size, void* d_ws, size_t ws_size,
                              hipStream_t stream) {
  const float* x = (const float*)d_in[0];
  const float* wq = (const float*)d_in[1];
  const float* bq = (const float*)d_in[2];
  const float* wk = (const float*)d_in[3];
  const float* bk = (const float*)d_in[4];
  const float* wv = (const float*)d_in[5];
  const float* bv = (const float*)d_in[6];
  const float* wo = (const float*)d_in[7];
  const float* bo = (const float*)d_in[8];
  float* out = (float*)d_out;

  char* ws = (char*)d_ws;
  size_t off = 0;
  auto carve = [&](size_t bytes) -> u16* {
    u16* p = (u16*)(ws + off);
    off += (bytes + 255) & ~(size_t)255;
    return p;
  };
  u16* xb = carve((size_t)8192 * 768 * 2);
  u16* wt = carve((size_t)2304 * 768 * 2);
  u16* wot = carve((size_t)768 * 768 * 2);
  float* qkvb = (float*)carve((size_t)2304 * 4);
  u16* qw = carve((size_t)BB * NH * SEQ * 64 * 2);
  u16* kw = carve((size_t)BB * NH * SEQ * 64 * 2);
  u16* vw = carve((size_t)BB * NH * SEQ * 64 * 2);
  u16* zw = carve((size_t)8192 * 768 * 2);
  if (ws_size < off) return;

  prep_kernel<<<dim3(13056), dim3(256), 0, stream>>>(x, wq, wk, wv, wo, bq, bk, bv,
                                                     xb, wt, wot, qkvb);
  gemm_qkv_kernel<<<dim3(1152), dim3(256), 0, stream>>>(wt, xb, qkvb, qw, kw, vw);
  attn_kernel<<<dim3(768), dim3(256), 0, stream>>>(qw, kw, vw, zw);
  gemm_out_kernel<<<dim3(384), dim3(256), 0, stream>>>(zw, wot, bo, out);
}

// Round 12
// 158.787 us; speedup vs baseline: 1.2658x; 1.2658x over previous
//
#include <hip/hip_runtime.h>

typedef unsigned short u16;
typedef __bf16 bf16x8 __attribute__((ext_vector_type(8)));
typedef float f32x4 __attribute__((ext_vector_type(4)));

#define D_MODEL 768
#define NH 12
#define SEQ 2048
#define BB 4
// 1/sqrt(64) * log2(e): softmax runs in exp2 domain (folded into W_Q, b_Q)
#define QSCALE 0.18033688011112042f
#define FIXM 8.0f  // fixed softmax max (exp2 domain); scores ~N(0,0.44)

__device__ __forceinline__ u16 f2b(float f) {
  __bf16 h = (__bf16)f;
  return __builtin_bit_cast(u16, h);
}

__device__ __forceinline__ void gload16(const void* g, void* l) {
  __builtin_amdgcn_global_load_lds((__attribute__((address_space(1))) void*)g,
                                   (__attribute__((address_space(3))) void*)l, 16, 0, 0);
}

__device__ __forceinline__ f32x4 mm16(bf16x8 a, bf16x8 b, f32x4 c) {
  return __builtin_amdgcn_mfma_f32_16x16x32_bf16(a, b, c, 0, 0, 0);
}

// ---------------- prep: cast x, pack weights, pack biases ----------------
__global__ void prep_kernel(const float* __restrict__ x, const float* __restrict__ wq,
                            const float* __restrict__ wk, const float* __restrict__ wv,
                            const float* __restrict__ wo, const float* __restrict__ bq,
                            const float* __restrict__ bk, const float* __restrict__ bv,
                            u16* __restrict__ xb, u16* __restrict__ wt,
                            u16* __restrict__ wot, float* __restrict__ qkvb) {
  const int bid = blockIdx.x;
  if (bid < 6144) {
    int i = (bid * 256 + threadIdx.x) * 4;
    float4 v = *(const float4*)&x[i];
    ushort4 o;
    o.x = f2b(v.x); o.y = f2b(v.y); o.z = f2b(v.z); o.w = f2b(v.w);
    *(ushort4*)&xb[i] = o;
  } else {
    int i = (bid - 6144) * 256 + threadIdx.x;
    {
      int cp = i / 768, d = i % 768;
      int proj = cp / 768, c = cp % 768, h = c / 64, e = c % 64;
      const float* W = (proj == 0) ? wq : ((proj == 1) ? wk : wv);
      float v = W[(size_t)h * 49152 + d * 64 + e];
      if (proj == 0) v *= QSCALE;
      wt[i] = f2b(v);
    }
    if (i < 768 * 768) {
      int rp = i / 768, d = i % 768;
      wot[i] = f2b(wo[(size_t)d * 768 + rp]);  // wot[d'][c]: rp=row d', d=col c
    }
    if (i < 2304) {
      int proj = i / 768, c = i % 768;
      float v = (proj == 0) ? bq[c] * QSCALE : ((proj == 1) ? bk[c] : bv[c]);
      qkvb[i] = v;
    }
  }
}

// ---------------- fused QKV GEMM — 256x128 tile, 8-phase fine interleave ---------
// C[c' 2304][token 8192] = wt * xb^T. 512 threads = 8 waves of 64x64 output.
// BK=64 -> 12 K-tiles; per K-tile 2 phases: {8 ds_read_b128; 3 gload16 (kt+2);
// [vmcnt(6) at phase B]; barrier; 16 MFMA (setprio); barrier}. 3-buffer LDS
// (144KB) so staging targets a buffer no wave is reading. Counted vmcnt only.
__global__ __launch_bounds__(512) void gemm_qkv_kernel(
    const u16* __restrict__ A, const u16* __restrict__ Bt,
    const float* __restrict__ qkvb, u16* __restrict__ qw, u16* __restrict__ kw,
    u16* __restrict__ vw) {
  __shared__ u16 lds[73728];  // A bufs: [b*16384], 3x32KB; B bufs: [49152+b*8192], 3x16KB
  const int tid = threadIdx.x;
  const int w = tid >> 6, lane = tid & 63;
  const int lg = lane >> 4, cl = lane & 15;
  // XCD-chunked swizzle: 576 blocks, 72/XCD; bm fast (wt panel L2-resident)
  const int L = blockIdx.x;
  const int v = (L & 7) * 72 + (L >> 3);
  const int bm = v % 9, bn = v / 9;           // bm: 256-row c' tile, bn: 128-token tile
  const int wr = w >> 1, wc = w & 1;          // wave: 64 c'-rows x 64 tokens
  const int NT = 12;                          // 768 / 64

  f32x4 vzero = {0.f, 0.f, 0.f, 0.f};
  f32x4 acc[4][4];
#pragma unroll
  for (int mi = 0; mi < 4; mi++)
#pragma unroll
    for (int ni = 0; ni < 4; ni++) acc[mi][ni] = vzero;

  const u16* aB = A + (size_t)bm * 256 * D_MODEL;
  const u16* bB = Bt + (size_t)bn * 128 * D_MODEL;
  const int l8 = lane >> 3, l7 = lane & 7;

  // stage half of K-tile kt into buf: half 0 = A rows (w*4+{0,1})*8 + B rows (w*2)*8;
  // half 1 = A rows (w*4+{2,3})*8 + B rows (w*2+1)*8. 3 gload16 per call.
  auto stage = [&](int buf, int kt, int half) {
    const int kof = kt * 64;
#pragma unroll
    for (int j2 = 0; j2 < 2; j2++) {
      const int r0 = (w * 4 + half * 2 + j2) * 8;  // 0..248
      gload16(aB + (size_t)(r0 + l8) * D_MODEL + kof + l7 * 8,
              &lds[buf * 16384 + r0 * 64]);
    }
    const int r0b = (w * 2 + half) * 8;  // 0..120
    gload16(bB + (size_t)(r0b + l8) * D_MODEL + kof + l7 * 8,
            &lds[49152 + buf * 8192 + r0b * 64]);
  };

  // prologue: K-tiles 0,1 fully staged; wait tile 0 (6 newest = tile 1 in flight)
  stage(0, 0, 0); stage(0, 0, 1);
  stage(1, 1, 0); stage(1, 1, 1);
  asm volatile("s_waitcnt vmcnt(6)" ::: "memory");
  __builtin_amdgcn_s_barrier();

  for (int kt = 0; kt < NT; ++kt) {
    const int cA = (kt % 3) * 16384;
    const int cB = 49152 + (kt % 3) * 8192;
    const int nbuf = (kt + 2) % 3;
#pragma unroll
    for (int ks = 0; ks < 2; ks++) {
      bf16x8 af[4], bf4[4];
#pragma unroll
      for (int mi = 0; mi < 4; mi++)
        af[mi] = *(const bf16x8*)&lds[cA + (wr * 64 + mi * 16 + cl) * 64 + ks * 32 + lg * 8];
#pragma unroll
      for (int ni = 0; ni < 4; ni++)
        bf4[ni] = *(const bf16x8*)&lds[cB + (wc * 64 + ni * 16 + cl) * 64 + ks * 32 + lg * 8];
      if (kt + 2 < NT) stage(nbuf, kt + 2, ks);
      if (ks == 1) {  // once per K-tile: next tile's data must be landed before kt+1
        if (kt + 2 < NT) asm volatile("s_waitcnt vmcnt(6)" ::: "memory");
        else asm volatile("s_waitcnt vmcnt(0)" ::: "memory");
      }
      __builtin_amdgcn_s_barrier();
      __builtin_amdgcn_s_setprio(1);
#pragma unroll
      for (int mi = 0; mi < 4; mi++)
#pragma unroll
        for (int ni = 0; ni < 4; ni++)
          acc[mi][ni] = mm16(af[mi], bf4[ni], acc[mi][ni]);
      __builtin_amdgcn_s_setprio(0);
      __builtin_amdgcn_s_barrier();
    }
  }

  __syncthreads();  // staging LDS now reusable as epilogue scratch
  u16* lw = &lds[w * 4096];  // 8KB per-wave scratch
  const int cm = bm * 256 + wr * 64;  // c' base: exactly one (proj, head)
  const int cn = bn * 128 + wc * 64;  // token base: within one batch b
  const int proj = cm / 768;
  const int h = (cm % 768) >> 6;
  const int b = cn >> 11, s_base = cn & 2047;
  const int rlo = lane >> 3, q8 = lane & 7;

  float bz[4][4];
#pragma unroll
  for (int mi = 0; mi < 4; mi++) {
    float4 b4 = *(const float4*)&qkvb[cm + mi * 16 + lg * 4];
    bz[mi][0] = b4.x; bz[mi][1] = b4.y; bz[mi][2] = b4.z; bz[mi][3] = b4.w;
  }

  if (proj < 2) {
    // LDS [s_local][e x 128B]; acc row = e, col = s -> pack 4 e's per write
#pragma unroll
    for (int mi = 0; mi < 4; mi++) {
      const int e0 = mi * 16 + lg * 4;
#pragma unroll
      for (int ni = 0; ni < 4; ni++) {
        const int s_l = ni * 16 + cl;
        ushort4 pk;
        pk.x = f2b(acc[mi][ni][0] + bz[mi][0]);
        pk.y = f2b(acc[mi][ni][1] + bz[mi][1]);
        pk.z = f2b(acc[mi][ni][2] + bz[mi][2]);
        pk.w = f2b(acc[mi][ni][3] + bz[mi][3]);
        *(ushort4*)&lw[(s_l * 128 + ((e0 * 2) ^ ((s_l & 7) << 4))) >> 1] = pk;
      }
    }
    u16* dst = ((proj == 0) ? qw : kw) + (((size_t)(b * NH + h) * SEQ + s_base) << 6);
#pragma unroll
    for (int it = 0; it < 8; it++) {
      const int row = it * 8 + rlo;
      *(bf16x8*)&dst[row * 64 + q8 * 8] =
          *(const bf16x8*)&lw[(row * 128 + ((q8 * 16) ^ ((row & 7) << 4))) >> 1];
    }
  } else {
    // V: LDS [e][s x 128B]; coalesced b128 readout along s
#pragma unroll
    for (int mi = 0; mi < 4; mi++)
#pragma unroll
      for (int ni = 0; ni < 4; ni++) {
        const int s_l = ni * 16 + cl;
#pragma unroll
        for (int r = 0; r < 4; r++) {
          const int e_l = mi * 16 + lg * 4 + r;
          lw[(e_l * 128 + ((s_l * 2) ^ ((e_l & 7) << 4))) >> 1] =
              f2b(acc[mi][ni][r] + bz[mi][r]);
        }
      }
    u16* dst = vw + (((size_t)(b * NH + h)) << 17) + s_base;
#pragma unroll
    for (int it = 0; it < 8; it++) {
      const int row = it * 8 + rlo;  // e
      *(bf16x8*)&dst[((size_t)row << 11) + q8 * 8] =
          *(const bf16x8*)&lw[(row * 128 + ((q8 * 16) ^ ((row & 7) << 4))) >> 1];
    }
  }
}

// ---------------- out-proj GEMM: out[8192 x 768] = zw * wot^T + b_O (R8) --------
__global__ __launch_bounds__(256) void gemm_out_kernel(
    const u16* __restrict__ A, const u16* __restrict__ Bt,
    const float* __restrict__ bias0, float* __restrict__ outf) {
  __shared__ u16 lds[16384];
  const int tid = threadIdx.x;
  const int w = tid >> 6, lane = tid & 63;
  const int lg = lane >> 4, cl = lane & 15;
  const int L = blockIdx.x;
  const int v = (L & 7) * 48 + (L >> 3);
  const int bn = v % 6, bm = v / 6;
  const int wr = w >> 1, wc = w & 1;
  const int NK = D_MODEL / 32;

  f32x4 vzero = {0.f, 0.f, 0.f, 0.f};
  f32x4 acc[4][4];
#pragma unroll
  for (int mi = 0; mi < 4; mi++)
#pragma unroll
    for (int ni = 0; ni < 4; ni++) acc[mi][ni] = vzero;

  const u16* aB = A + (size_t)bm * 128 * D_MODEL;
  const u16* bB = Bt + (size_t)bn * 128 * D_MODEL;

  auto stage = [&](int buf, int kt) {
    const int kof = kt * 32 + w * 8;
    gload16(aB + (size_t)(lane)*D_MODEL + kof, &lds[buf * 4096 + (w * 128 + 0) * 8]);
    gload16(aB + (size_t)(64 + lane) * D_MODEL + kof,
            &lds[buf * 4096 + (w * 128 + 64) * 8]);
    gload16(bB + (size_t)(lane)*D_MODEL + kof,
            &lds[8192 + buf * 4096 + (w * 128 + 0) * 8]);
    gload16(bB + (size_t)(64 + lane) * D_MODEL + kof,
            &lds[8192 + buf * 4096 + (w * 128 + 64) * 8]);
  };

  stage(0, 0);
  stage(1, 1);
  for (int kt = 0; kt < NK; ++kt) {
    const int cur = kt & 1;
    if (kt < NK - 1) asm volatile("s_waitcnt vmcnt(4)" ::: "memory");
    else asm volatile("s_waitcnt vmcnt(0)" ::: "memory");
    __builtin_amdgcn_s_barrier();

    bf16x8 af[4], bf4[4];
#pragma unroll
    for (int mi = 0; mi < 4; mi++)
      af[mi] = *(const bf16x8*)&lds[cur * 4096 + (lg * 128 + wr * 64 + mi * 16 + cl) * 8];
#pragma unroll
    for (int ni = 0; ni < 4; ni++)
      bf4[ni] = *(const bf16x8*)&lds[8192 + cur * 4096 +
                                     (lg * 128 + wc * 64 + ni * 16 + cl) * 8];
    __builtin_amdgcn_s_setprio(1);
#pragma unroll
    for (int mi = 0; mi < 4; mi++)
#pragma unroll
      for (int ni = 0; ni < 4; ni++)
        acc[mi][ni] = mm16(af[mi], bf4[ni], acc[mi][ni]);
    __builtin_amdgcn_s_setprio(0);

    asm volatile("s_waitcnt lgkmcnt(0)" ::: "memory");
    __builtin_amdgcn_s_barrier();
    if (kt + 2 < NK) stage(cur, kt + 2);
  }

  __syncthreads();
  u16* lw = &lds[w * 4096];
  float* lwf = (float*)lw;
  const int m_base = bm * 128 + wr * 64;
  const int n0 = bn * 128 + wc * 64;
  const int rlo = lane >> 3, q8 = lane & 7;
#pragma unroll
  for (int hh = 0; hh < 2; hh++) {
#pragma unroll
    for (int nn = 0; nn < 2; nn++) {
      const int ni = hh * 2 + nn;
      const float bz = bias0[n0 + ni * 16 + cl];
      const int col = nn * 16 + cl;
#pragma unroll
      for (int mi = 0; mi < 4; mi++)
#pragma unroll
        for (int r = 0; r < 4; r++) {
          const int row = mi * 16 + lg * 4 + r;
          lwf[(row * 128 + ((col * 4) ^ ((row & 7) << 4))) >> 2] = acc[mi][ni][r] + bz;
        }
    }
#pragma unroll
    for (int it = 0; it < 8; it++) {
      const int row = it * 8 + rlo;
      const int byt = row * 128 + ((q8 * 16) ^ ((row & 7) << 4));
      *(float4*)&outf[(size_t)(m_base + row) * D_MODEL + n0 + hh * 32 + q8 * 4] =
          *(const float4*)((const char*)lwf + byt);
    }
  }
}

// ---------------- flash attention (R8: 2-buffer, 40KB, fixed-max) ----------------
__global__ __launch_bounds__(256) void attn_kernel(
    const u16* __restrict__ q_ws, const u16* __restrict__ k_ws,
    const u16* __restrict__ vT_ws, u16* __restrict__ z_ws) {
  __shared__ u16 lk[2][4096];  // [buf][e-chunk][k-row][8 e]
  __shared__ u16 lv[2][4096];  // [buf][kk-chunk][e-row][8 kk]
  __shared__ u16 lp[4096];     // per-wave P [16 q][64 kk] bf16, XOR-swizzled
  const int tid = threadIdx.x, w = tid >> 6, lane = tid & 63;
  const int lg = lane >> 4, cl = lane & 15, c7 = cl & 7;
  const int L = blockIdx.x;
  const int vv = (L & 7) * 96 + (L >> 3);
  const int pair = vv & 15, bh = vv >> 4;
  const u16* qp = q_ws + (size_t)bh * SEQ * 64;
  const u16* kp = k_ws + (size_t)bh * SEQ * 64;
  const u16* vp = vT_ws + (size_t)bh * 64 * SEQ;
  const int b = bh / NH, h = bh % NH;

  for (int sel = 0; sel < 2; ++sel) {
    const int qt = (sel == 0) ? pair : 31 - pair;
    const int q0 = qt * 64;
    const int qabs = q0 + w * 16 + cl;  // this lane's q-row

    bf16x8 qf[2];
#pragma unroll
    for (int ks = 0; ks < 2; ks++)
      qf[ks] = *(const bf16x8*)&qp[(size_t)(q0 + w * 16 + cl) * 64 + ks * 32 + lg * 8];

    f32x4 vzero = {0.f, 0.f, 0.f, 0.f};
    f32x4 accO[4];
#pragma unroll
    for (int nb = 0; nb < 4; nb++) accO[nb] = vzero;
    float lrun = 0.f;

#pragma unroll
    for (int c2 = 0; c2 < 2; c2++) {
      const int ch = w + c2 * 4;
      gload16(kp + (size_t)(lane)*64 + ch * 8, &lk[0][ch * 64 * 8]);
      gload16(vp + (size_t)lane * SEQ + ch * 8, &lv[0][ch * 64 * 8]);
    }
    asm volatile("s_waitcnt vmcnt(0)" ::: "memory");
    __builtin_amdgcn_s_barrier();

    for (int kt = 0; kt <= qt; ++kt) {
      const int cur = kt & 1;
      const int k0 = kt * 64;
      if (kt < qt) {
        const int kn = k0 + 64;
#pragma unroll
        for (int c2 = 0; c2 < 2; c2++) {
          const int ch = w + c2 * 4;
          gload16(kp + (size_t)(kn + lane) * 64 + ch * 8, &lk[cur ^ 1][ch * 64 * 8]);
          gload16(vp + (size_t)lane * SEQ + kn + ch * 8, &lv[cur ^ 1][ch * 64 * 8]);
        }
      }

      // S^T = K * Q^T: D row = kk (cb*16+lg*4+r), col = q (cl)
      f32x4 sa[4];
#pragma unroll
      for (int cb = 0; cb < 4; cb++) sa[cb] = vzero;
      __builtin_amdgcn_s_setprio(1);
#pragma unroll
      for (int ks = 0; ks < 2; ks++) {
#pragma unroll
        for (int cb = 0; cb < 4; cb++) {
          bf16x8 kf = *(const bf16x8*)&lk[cur][((ks * 4 + lg) * 64 + cb * 16 + cl) * 8];
          sa[cb] = mm16(kf, qf[ks], sa[cb]);
        }
      }
      __builtin_amdgcn_s_setprio(0);
      if (kt == qt) {  // diagonal tile: causal mask (kk > q)
#pragma unroll
        for (int cb = 0; cb < 4; cb++)
#pragma unroll
          for (int r = 0; r < 4; r++)
            if (k0 + cb * 16 + lg * 4 + r > qabs) sa[cb][r] = -1e30f;
      }

      // fixed-max softmax: p = exp2(s - FIXM)
      float ps = 0.f;
#pragma unroll
      for (int cb = 0; cb < 4; cb++) {
        float p0 = __builtin_amdgcn_exp2f(sa[cb][0] - FIXM);
        float p1 = __builtin_amdgcn_exp2f(sa[cb][1] - FIXM);
        float p2 = __builtin_amdgcn_exp2f(sa[cb][2] - FIXM);
        float p3 = __builtin_amdgcn_exp2f(sa[cb][3] - FIXM);
        ps += (p0 + p1) + (p2 + p3);
        ushort4 pk;
        pk.x = f2b(p0); pk.y = f2b(p1); pk.z = f2b(p2); pk.w = f2b(p3);
        *(ushort4*)&lp[w * 1024 + (cl * 128 + ((cb * 32 + lg * 8) ^ (c7 << 4))) / 2] = pk;
      }
      ps += __shfl_xor(ps, 16);
      ps += __shfl_xor(ps, 32);
      lrun += ps;

      // PV: A = P (row q=cl), B = V^T
      __builtin_amdgcn_s_setprio(1);
#pragma unroll
      for (int ks = 0; ks < 2; ks++) {
        bf16x8 pf = *(const bf16x8*)&lp[w * 1024 +
                                        (cl * 128 + ((ks * 64 + lg * 16) ^ (c7 << 4))) / 2];
#pragma unroll
        for (int nb = 0; nb < 4; nb++) {
          bf16x8 vf = *(const bf16x8*)&lv[cur][((ks * 4 + lg) * 64 + nb * 16 + cl) * 8];
          accO[nb] = mm16(pf, vf, accO[nb]);
        }
      }
      __builtin_amdgcn_s_setprio(0);

      asm volatile("s_waitcnt vmcnt(0)" ::: "memory");
      __builtin_amdgcn_s_barrier();
    }

    float inv[4];
#pragma unroll
    for (int r = 0; r < 4; r++) inv[r] = 1.f / __shfl(lrun, lg * 4 + r);
#pragma unroll
    for (int nb = 0; nb < 4; nb++)
#pragma unroll
      for (int r = 0; r < 4; r++) {
        const int qrow = q0 + w * 16 + lg * 4 + r;
        z_ws[((size_t)b * SEQ + qrow) * D_MODEL + h * 64 + nb * 16 + cl] =
            f2b(accO[nb][r] * inv[r]);
      }
  }
}

// ---------------- launch ----------------
extern "C" void kernel_launch(void* const* d_in, const int* in_sizes, int n_in,
                              void* d_out, int out_size, void* d_ws, size_t ws_size,
                              hipStream_t stream) {
  const float* x = (const float*)d_in[0];
  const float* wq = (const float*)d_in[1];
  const float* bq = (const float*)d_in[2];
  const float* wk = (const float*)d_in[3];
  const float* bk = (const float*)d_in[4];
  const float* wv = (const float*)d_in[5];
  const float* bv = (const float*)d_in[6];
  const float* wo = (const float*)d_in[7];
  const float* bo = (const float*)d_in[8];
  float* out = (float*)d_out;

  char* ws = (char*)d_ws;
  size_t off = 0;
  auto carve = [&](size_t bytes) -> u16* {
    u16* p = (u16*)(ws + off);
    off += (bytes + 255) & ~(size_t)255;
    return p;
  };
  u16* xb = carve((size_t)8192 * 768 * 2);
  u16* wt = carve((size_t)2304 * 768 * 2);
  u16* wot = carve((size_t)768 * 768 * 2);
  float* qkvb = (float*)carve((size_t)2304 * 4);
  u16* qw = carve((size_t)BB * NH * SEQ * 64 * 2);
  u16* kw = carve((size_t)BB * NH * SEQ * 64 * 2);
  u16* vw = carve((size_t)BB * NH * SEQ * 64 * 2);
  u16* zw = carve((size_t)8192 * 768 * 2);
  if (ws_size < off) return;

  prep_kernel<<<dim3(13056), dim3(256), 0, stream>>>(x, wq, wk, wv, wo, bq, bk, bv,
                                                     xb, wt, wot, qkvb);
  gemm_qkv_kernel<<<dim3(576), dim3(512), 0, stream>>>(wt, xb, qkvb, qw, kw, vw);
  attn_kernel<<<dim3(768), dim3(256), 0, stream>>>(qw, kw, vw, zw);
  gemm_out_kernel<<<dim3(384), dim3(256), 0, stream>>>(zw, wot, bo, out);
}

// Round 13
// 150.964 us; speedup vs baseline: 1.3313x; 1.0518x over previous
//
#include <hip/hip_runtime.h>

typedef unsigned short u16;
typedef __bf16 bf16x8 __attribute__((ext_vector_type(8)));
typedef float f32x4 __attribute__((ext_vector_type(4)));

#define D_MODEL 768
#define NH 12
#define SEQ 2048
#define BB 4
// 1/sqrt(64) * log2(e): softmax runs in exp2 domain (folded into W_Q, b_Q)
#define QSCALE 0.18033688011112042f
#define FIXM 8.0f  // fixed softmax max (exp2 domain); scores ~N(0,0.44)

__device__ __forceinline__ u16 f2b(float f) {
  __bf16 h = (__bf16)f;
  return __builtin_bit_cast(u16, h);
}

__device__ __forceinline__ void gload16(const void* g, void* l) {
  __builtin_amdgcn_global_load_lds((__attribute__((address_space(1))) void*)g,
                                   (__attribute__((address_space(3))) void*)l, 16, 0, 0);
}

__device__ __forceinline__ f32x4 mm16(bf16x8 a, bf16x8 b, f32x4 c) {
  return __builtin_amdgcn_mfma_f32_16x16x32_bf16(a, b, c, 0, 0, 0);
}

// ---------------- prep: cast x, pack weights, pack biases ----------------
__global__ void prep_kernel(const float* __restrict__ x, const float* __restrict__ wq,
                            const float* __restrict__ wk, const float* __restrict__ wv,
                            const float* __restrict__ wo, const float* __restrict__ bq,
                            const float* __restrict__ bk, const float* __restrict__ bv,
                            u16* __restrict__ xb, u16* __restrict__ wt,
                            u16* __restrict__ wot, float* __restrict__ qkvb) {
  const int bid = blockIdx.x;
  if (bid < 6144) {
    int i = (bid * 256 + threadIdx.x) * 4;
    float4 v = *(const float4*)&x[i];
    ushort4 o;
    o.x = f2b(v.x); o.y = f2b(v.y); o.z = f2b(v.z); o.w = f2b(v.w);
    *(ushort4*)&xb[i] = o;
  } else {
    int i = (bid - 6144) * 256 + threadIdx.x;
    {
      int cp = i / 768, d = i % 768;
      int proj = cp / 768, c = cp % 768, h = c / 64, e = c % 64;
      const float* W = (proj == 0) ? wq : ((proj == 1) ? wk : wv);
      float v = W[(size_t)h * 49152 + d * 64 + e];
      if (proj == 0) v *= QSCALE;
      wt[i] = f2b(v);
    }
    if (i < 768 * 768) {
      int rp = i / 768, d = i % 768;
      wot[i] = f2b(wo[(size_t)d * 768 + rp]);  // wot[d'][c]: rp=row d', d=col c
    }
    if (i < 2304) {
      int proj = i / 768, c = i % 768;
      float v = (proj == 0) ? bq[c] * QSCALE : ((proj == 1) ? bk[c] : bv[c]);
      qkvb[i] = v;
    }
  }
}

// ---------------- fused QKV GEMM — 256x128 tile, 8-phase fine interleave ---------
// (R12, verified) 512 threads = 8 waves of 64x64 output; BK=64, 3-buffer LDS.
__global__ __launch_bounds__(512) void gemm_qkv_kernel(
    const u16* __restrict__ A, const u16* __restrict__ Bt,
    const float* __restrict__ qkvb, u16* __restrict__ qw, u16* __restrict__ kw,
    u16* __restrict__ vw) {
  __shared__ u16 lds[73728];  // A bufs: [b*16384], 3x32KB; B bufs: [49152+b*8192], 3x16KB
  const int tid = threadIdx.x;
  const int w = tid >> 6, lane = tid & 63;
  const int lg = lane >> 4, cl = lane & 15;
  const int L = blockIdx.x;
  const int v = (L & 7) * 72 + (L >> 3);
  const int bm = v % 9, bn = v / 9;
  const int wr = w >> 1, wc = w & 1;
  const int NT = 12;

  f32x4 vzero = {0.f, 0.f, 0.f, 0.f};
  f32x4 acc[4][4];
#pragma unroll
  for (int mi = 0; mi < 4; mi++)
#pragma unroll
    for (int ni = 0; ni < 4; ni++) acc[mi][ni] = vzero;

  const u16* aB = A + (size_t)bm * 256 * D_MODEL;
  const u16* bB = Bt + (size_t)bn * 128 * D_MODEL;
  const int l8 = lane >> 3, l7 = lane & 7;

  auto stage = [&](int buf, int kt, int half) {
    const int kof = kt * 64;
#pragma unroll
    for (int j2 = 0; j2 < 2; j2++) {
      const int r0 = (w * 4 + half * 2 + j2) * 8;
      gload16(aB + (size_t)(r0 + l8) * D_MODEL + kof + l7 * 8,
              &lds[buf * 16384 + r0 * 64]);
    }
    const int r0b = (w * 2 + half) * 8;
    gload16(bB + (size_t)(r0b + l8) * D_MODEL + kof + l7 * 8,
            &lds[49152 + buf * 8192 + r0b * 64]);
  };

  stage(0, 0, 0); stage(0, 0, 1);
  stage(1, 1, 0); stage(1, 1, 1);
  asm volatile("s_waitcnt vmcnt(6)" ::: "memory");
  __builtin_amdgcn_s_barrier();

  for (int kt = 0; kt < NT; ++kt) {
    const int cA = (kt % 3) * 16384;
    const int cB = 49152 + (kt % 3) * 8192;
    const int nbuf = (kt + 2) % 3;
#pragma unroll
    for (int ks = 0; ks < 2; ks++) {
      bf16x8 af[4], bf4[4];
#pragma unroll
      for (int mi = 0; mi < 4; mi++)
        af[mi] = *(const bf16x8*)&lds[cA + (wr * 64 + mi * 16 + cl) * 64 + ks * 32 + lg * 8];
#pragma unroll
      for (int ni = 0; ni < 4; ni++)
        bf4[ni] = *(const bf16x8*)&lds[cB + (wc * 64 + ni * 16 + cl) * 64 + ks * 32 + lg * 8];
      if (kt + 2 < NT) stage(nbuf, kt + 2, ks);
      if (ks == 1) {
        if (kt + 2 < NT) asm volatile("s_waitcnt vmcnt(6)" ::: "memory");
        else asm volatile("s_waitcnt vmcnt(0)" ::: "memory");
      }
      __builtin_amdgcn_s_barrier();
      __builtin_amdgcn_s_setprio(1);
#pragma unroll
      for (int mi = 0; mi < 4; mi++)
#pragma unroll
        for (int ni = 0; ni < 4; ni++)
          acc[mi][ni] = mm16(af[mi], bf4[ni], acc[mi][ni]);
      __builtin_amdgcn_s_setprio(0);
      __builtin_amdgcn_s_barrier();
    }
  }

  __syncthreads();
  u16* lw = &lds[w * 4096];
  const int cm = bm * 256 + wr * 64;
  const int cn = bn * 128 + wc * 64;
  const int proj = cm / 768;
  const int h = (cm % 768) >> 6;
  const int b = cn >> 11, s_base = cn & 2047;
  const int rlo = lane >> 3, q8 = lane & 7;

  float bz[4][4];
#pragma unroll
  for (int mi = 0; mi < 4; mi++) {
    float4 b4 = *(const float4*)&qkvb[cm + mi * 16 + lg * 4];
    bz[mi][0] = b4.x; bz[mi][1] = b4.y; bz[mi][2] = b4.z; bz[mi][3] = b4.w;
  }

  if (proj < 2) {
#pragma unroll
    for (int mi = 0; mi < 4; mi++) {
      const int e0 = mi * 16 + lg * 4;
#pragma unroll
      for (int ni = 0; ni < 4; ni++) {
        const int s_l = ni * 16 + cl;
        ushort4 pk;
        pk.x = f2b(acc[mi][ni][0] + bz[mi][0]);
        pk.y = f2b(acc[mi][ni][1] + bz[mi][1]);
        pk.z = f2b(acc[mi][ni][2] + bz[mi][2]);
        pk.w = f2b(acc[mi][ni][3] + bz[mi][3]);
        *(ushort4*)&lw[(s_l * 128 + ((e0 * 2) ^ ((s_l & 7) << 4))) >> 1] = pk;
      }
    }
    u16* dst = ((proj == 0) ? qw : kw) + (((size_t)(b * NH + h) * SEQ + s_base) << 6);
#pragma unroll
    for (int it = 0; it < 8; it++) {
      const int row = it * 8 + rlo;
      *(bf16x8*)&dst[row * 64 + q8 * 8] =
          *(const bf16x8*)&lw[(row * 128 + ((q8 * 16) ^ ((row & 7) << 4))) >> 1];
    }
  } else {
#pragma unroll
    for (int mi = 0; mi < 4; mi++)
#pragma unroll
      for (int ni = 0; ni < 4; ni++) {
        const int s_l = ni * 16 + cl;
#pragma unroll
        for (int r = 0; r < 4; r++) {
          const int e_l = mi * 16 + lg * 4 + r;
          lw[(e_l * 128 + ((s_l * 2) ^ ((e_l & 7) << 4))) >> 1] =
              f2b(acc[mi][ni][r] + bz[mi][r]);
        }
      }
    u16* dst = vw + (((size_t)(b * NH + h)) << 17) + s_base;
#pragma unroll
    for (int it = 0; it < 8; it++) {
      const int row = it * 8 + rlo;
      *(bf16x8*)&dst[((size_t)row << 11) + q8 * 8] =
          *(const bf16x8*)&lw[(row * 128 + ((q8 * 16) ^ ((row & 7) << 4))) >> 1];
    }
  }
}

// ---------------- out-proj GEMM — 256x128 tile, 8-phase fine interleave ----------
// out[8192 x 768] = zw * wot^T + b_O. Same schedule as gemm_qkv; fp32 epilogue.
__global__ __launch_bounds__(512) void gemm_out_kernel(
    const u16* __restrict__ A, const u16* __restrict__ Bt,
    const float* __restrict__ bias0, float* __restrict__ outf) {
  __shared__ u16 lds[73728];
  const int tid = threadIdx.x;
  const int w = tid >> 6, lane = tid & 63;
  const int lg = lane >> 4, cl = lane & 15;
  const int L = blockIdx.x;  // 192 blocks
  const int v = (L & 7) * 24 + (L >> 3);
  const int bm = v / 6, bn = v % 6;  // bm: 256-token tile, bn: 128-col tile
  const int wr = w >> 1, wc = w & 1;
  const int NT = 12;

  f32x4 vzero = {0.f, 0.f, 0.f, 0.f};
  f32x4 acc[4][4];
#pragma unroll
  for (int mi = 0; mi < 4; mi++)
#pragma unroll
    for (int ni = 0; ni < 4; ni++) acc[mi][ni] = vzero;

  const u16* aB = A + (size_t)bm * 256 * D_MODEL;
  const u16* bB = Bt + (size_t)bn * 128 * D_MODEL;
  const int l8 = lane >> 3, l7 = lane & 7;

  auto stage = [&](int buf, int kt, int half) {
    const int kof = kt * 64;
#pragma unroll
    for (int j2 = 0; j2 < 2; j2++) {
      const int r0 = (w * 4 + half * 2 + j2) * 8;
      gload16(aB + (size_t)(r0 + l8) * D_MODEL + kof + l7 * 8,
              &lds[buf * 16384 + r0 * 64]);
    }
    const int r0b = (w * 2 + half) * 8;
    gload16(bB + (size_t)(r0b + l8) * D_MODEL + kof + l7 * 8,
            &lds[49152 + buf * 8192 + r0b * 64]);
  };

  stage(0, 0, 0); stage(0, 0, 1);
  stage(1, 1, 0); stage(1, 1, 1);
  asm volatile("s_waitcnt vmcnt(6)" ::: "memory");
  __builtin_amdgcn_s_barrier();

  for (int kt = 0; kt < NT; ++kt) {
    const int cA = (kt % 3) * 16384;
    const int cB = 49152 + (kt % 3) * 8192;
    const int nbuf = (kt + 2) % 3;
#pragma unroll
    for (int ks = 0; ks < 2; ks++) {
      bf16x8 af[4], bf4[4];
#pragma unroll
      for (int mi = 0; mi < 4; mi++)
        af[mi] = *(const bf16x8*)&lds[cA + (wr * 64 + mi * 16 + cl) * 64 + ks * 32 + lg * 8];
#pragma unroll
      for (int ni = 0; ni < 4; ni++)
        bf4[ni] = *(const bf16x8*)&lds[cB + (wc * 64 + ni * 16 + cl) * 64 + ks * 32 + lg * 8];
      if (kt + 2 < NT) stage(nbuf, kt + 2, ks);
      if (ks == 1) {
        if (kt + 2 < NT) asm volatile("s_waitcnt vmcnt(6)" ::: "memory");
        else asm volatile("s_waitcnt vmcnt(0)" ::: "memory");
      }
      __builtin_amdgcn_s_barrier();
      __builtin_amdgcn_s_setprio(1);
#pragma unroll
      for (int mi = 0; mi < 4; mi++)
#pragma unroll
        for (int ni = 0; ni < 4; ni++)
          acc[mi][ni] = mm16(af[mi], bf4[ni], acc[mi][ni]);
      __builtin_amdgcn_s_setprio(0);
      __builtin_amdgcn_s_barrier();
    }
  }

  __syncthreads();
  u16* lw = &lds[w * 4096];
  float* lwf = (float*)lw;
  const int m_base = bm * 256 + wr * 64;
  const int n0 = bn * 128 + wc * 64;
  const int rlo = lane >> 3, q8 = lane & 7;
#pragma unroll
  for (int hh = 0; hh < 2; hh++) {
#pragma unroll
    for (int nn = 0; nn < 2; nn++) {
      const int ni = hh * 2 + nn;
      const float bz = bias0[n0 + ni * 16 + cl];
      const int col = nn * 16 + cl;
#pragma unroll
      for (int mi = 0; mi < 4; mi++)
#pragma unroll
        for (int r = 0; r < 4; r++) {
          const int row = mi * 16 + lg * 4 + r;
          lwf[(row * 128 + ((col * 4) ^ ((row & 7) << 4))) >> 2] = acc[mi][ni][r] + bz;
        }
    }
#pragma unroll
    for (int it = 0; it < 8; it++) {
      const int row = it * 8 + rlo;
      const int byt = row * 128 + ((q8 * 16) ^ ((row & 7) << 4));
      *(float4*)&outf[(size_t)(m_base + row) * D_MODEL + n0 + hh * 32 + q8 * 4] =
          *(const float4*)((const char*)lwf + byt);
    }
  }
}

// ---------------- flash attention (fixed-max + MFMA-ones row-sum) ----------------
// grid 768 XCD-chunked; block does q-tiles {p, 31-p}. Softmax denominator via
// ones-B-fragment MFMA: accS[r] = sum_kk P[q=lg*4+r][kk], accumulated across
// tiles in the accumulator — no v_add chain, no shuffles, no lrun state.
__global__ __launch_bounds__(256) void attn_kernel(
    const u16* __restrict__ q_ws, const u16* __restrict__ k_ws,
    const u16* __restrict__ vT_ws, u16* __restrict__ z_ws) {
  __shared__ u16 lk[2][4096];  // [buf][e-chunk][k-row][8 e]
  __shared__ u16 lv[2][4096];  // [buf][kk-chunk][e-row][8 kk]
  __shared__ u16 lp[4096];     // per-wave P [16 q][64 kk] bf16, XOR-swizzled
  const int tid = threadIdx.x, w = tid >> 6, lane = tid & 63;
  const int lg = lane >> 4, cl = lane & 15, c7 = cl & 7;
  const int L = blockIdx.x;
  const int vv = (L & 7) * 96 + (L >> 3);
  const int pair = vv & 15, bh = vv >> 4;
  const u16* qp = q_ws + (size_t)bh * SEQ * 64;
  const u16* kp = k_ws + (size_t)bh * SEQ * 64;
  const u16* vp = vT_ws + (size_t)bh * 64 * SEQ;
  const int b = bh / NH, h = bh % NH;

  const __bf16 one1 = (__bf16)1.0f;
  const bf16x8 vones = {one1, one1, one1, one1, one1, one1, one1, one1};

  for (int sel = 0; sel < 2; ++sel) {
    const int qt = (sel == 0) ? pair : 31 - pair;
    const int q0 = qt * 64;
    const int qabs = q0 + w * 16 + cl;  // this lane's q-row

    bf16x8 qf[2];
#pragma unroll
    for (int ks = 0; ks < 2; ks++)
      qf[ks] = *(const bf16x8*)&qp[(size_t)(q0 + w * 16 + cl) * 64 + ks * 32 + lg * 8];

    f32x4 vzero = {0.f, 0.f, 0.f, 0.f};
    f32x4 accO[4];
#pragma unroll
    for (int nb = 0; nb < 4; nb++) accO[nb] = vzero;
    f32x4 accS = vzero;  // row-sum accumulator: accS[r] = sum P[q=lg*4+r][*]

#pragma unroll
    for (int c2 = 0; c2 < 2; c2++) {
      const int ch = w + c2 * 4;
      gload16(kp + (size_t)(lane)*64 + ch * 8, &lk[0][ch * 64 * 8]);
      gload16(vp + (size_t)lane * SEQ + ch * 8, &lv[0][ch * 64 * 8]);
    }
    asm volatile("s_waitcnt vmcnt(0)" ::: "memory");
    __builtin_amdgcn_s_barrier();

    for (int kt = 0; kt <= qt; ++kt) {
      const int cur = kt & 1;
      const int k0 = kt * 64;
      if (kt < qt) {
        const int kn = k0 + 64;
#pragma unroll
        for (int c2 = 0; c2 < 2; c2++) {
          const int ch = w + c2 * 4;
          gload16(kp + (size_t)(kn + lane) * 64 + ch * 8, &lk[cur ^ 1][ch * 64 * 8]);
          gload16(vp + (size_t)lane * SEQ + kn + ch * 8, &lv[cur ^ 1][ch * 64 * 8]);
        }
      }

      // S^T = K * Q^T: D row = kk (cb*16+lg*4+r), col = q (cl)
      f32x4 sa[4];
#pragma unroll
      for (int cb = 0; cb < 4; cb++) sa[cb] = vzero;
      __builtin_amdgcn_s_setprio(1);
#pragma unroll
      for (int ks = 0; ks < 2; ks++) {
#pragma unroll
        for (int cb = 0; cb < 4; cb++) {
          bf16x8 kf = *(const bf16x8*)&lk[cur][((ks * 4 + lg) * 64 + cb * 16 + cl) * 8];
          sa[cb] = mm16(kf, qf[ks], sa[cb]);
        }
      }
      __builtin_amdgcn_s_setprio(0);
      if (kt == qt) {  // diagonal tile: causal mask (kk > q)
#pragma unroll
        for (int cb = 0; cb < 4; cb++)
#pragma unroll
          for (int r = 0; r < 4; r++)
            if (k0 + cb * 16 + lg * 4 + r > qabs) sa[cb][r] = -1e30f;
      }

      // fixed-max softmax: p = exp2(s - FIXM); pack to LDS (no sum here)
#pragma unroll
      for (int cb = 0; cb < 4; cb++) {
        float p0 = __builtin_amdgcn_exp2f(sa[cb][0] - FIXM);
        float p1 = __builtin_amdgcn_exp2f(sa[cb][1] - FIXM);
        float p2 = __builtin_amdgcn_exp2f(sa[cb][2] - FIXM);
        float p3 = __builtin_amdgcn_exp2f(sa[cb][3] - FIXM);
        ushort4 pk;
        pk.x = f2b(p0); pk.y = f2b(p1); pk.z = f2b(p2); pk.w = f2b(p3);
        *(ushort4*)&lp[w * 1024 + (cl * 128 + ((cb * 32 + lg * 8) ^ (c7 << 4))) / 2] = pk;
      }

      // PV + row-sum: A = P (row q=cl), B = V^T / ones
      __builtin_amdgcn_s_setprio(1);
#pragma unroll
      for (int ks = 0; ks < 2; ks++) {
        bf16x8 pf = *(const bf16x8*)&lp[w * 1024 +
                                        (cl * 128 + ((ks * 64 + lg * 16) ^ (c7 << 4))) / 2];
#pragma unroll
        for (int nb = 0; nb < 4; nb++) {
          bf16x8 vf = *(const bf16x8*)&lv[cur][((ks * 4 + lg) * 64 + nb * 16 + cl) * 8];
          accO[nb] = mm16(pf, vf, accO[nb]);
        }
        accS = mm16(pf, vones, accS);  // denominator, free of VALU
      }
      __builtin_amdgcn_s_setprio(0);

      asm volatile("s_waitcnt vmcnt(0)" ::: "memory");
      __builtin_amdgcn_s_barrier();
    }

    float inv[4];
#pragma unroll
    for (int r = 0; r < 4; r++) inv[r] = 1.f / accS[r];  // already per-q layout
#pragma unroll
    for (int nb = 0; nb < 4; nb++)
#pragma unroll
      for (int r = 0; r < 4; r++) {
        const int qrow = q0 + w * 16 + lg * 4 + r;
        z_ws[((size_t)b * SEQ + qrow) * D_MODEL + h * 64 + nb * 16 + cl] =
            f2b(accO[nb][r] * inv[r]);
      }
  }
}

// ---------------- launch ----------------
extern "C" void kernel_launch(void* const* d_in, const int* in_sizes, int n_in,
                              void* d_out, int out_size, void* d_ws, size_t ws_size,
                              hipStream_t stream) {
  const float* x = (const float*)d_in[0];
  const float* wq = (const float*)d_in[1];
  const float* bq = (const float*)d_in[2];
  const float* wk = (const float*)d_in[3];
  const float* bk = (const float*)d_in[4];
  const float* wv = (const float*)d_in[5];
  const float* bv = (const float*)d_in[6];
  const float* wo = (const float*)d_in[7];
  const float* bo = (const float*)d_in[8];
  float* out = (float*)d_out;

  char* ws = (char*)d_ws;
  size_t off = 0;
  auto carve = [&](size_t bytes) -> u16* {
    u16* p = (u16*)(ws + off);
    off += (bytes + 255) & ~(size_t)255;
    return p;
  };
  u16* xb = carve((size_t)8192 * 768 * 2);
  u16* wt = carve((size_t)2304 * 768 * 2);
  u16* wot = carve((size_t)768 * 768 * 2);
  float* qkvb = (float*)carve((size_t)2304 * 4);
  u16* qw = carve((size_t)BB * NH * SEQ * 64 * 2);
  u16* kw = carve((size_t)BB * NH * SEQ * 64 * 2);
  u16* vw = carve((size_t)BB * NH * SEQ * 64 * 2);
  u16* zw = carve((size_t)8192 * 768 * 2);
  if (ws_size < off) return;

  prep_kernel<<<dim3(13056), dim3(256), 0, stream>>>(x, wq, wk, wv, wo, bq, bk, bv,
                                                     xb, wt, wot, qkvb);
  gemm_qkv_kernel<<<dim3(576), dim3(512), 0, stream>>>(wt, xb, qkvb, qw, kw, vw);
  attn_kernel<<<dim3(768), dim3(256), 0, stream>>>(qw, kw, vw, zw);
  gemm_out_kernel<<<dim3(192), dim3(512), 0, stream>>>(zw, wot, bo, out);
}